// Round 2
// baseline (301.658 us; speedup 1.0000x reference)
//
#include <hip/hip_runtime.h>
#include <math.h>

// Problem constants (fixed by reference setup_inputs)
constexpr int Bv = 8;
constexpr int Sv = 4096;
constexpr int Dv = 512;
constexpr int NCv = 64;           // S-chunks for pass-1 partials
constexpr int SCv = Sv / NCv;     // 64 rows per chunk
constexpr int Pv = 98;            // sampled partitions
constexpr int Kv = 6;             // max parts per partition
constexpr int MAXPv = 100;

// Workspace layout. First 16 ints are ticket counters (zeroed by memset node):
//   ctr[0..7]  = per-batch arrival counters for k1's fused combine
//   ctr[8]     = global arrival counter for k3's fused final
// Float arrays start at float offset 16.
constexpr size_t OFF_MPART = 16;
constexpr size_t OFF_ZPART = OFF_MPART + (size_t)Bv * NCv * Dv;
constexpr size_t OFF_TPART = OFF_ZPART + (size_t)Bv * NCv * Dv;
constexpr size_t OFF_XMAX  = OFF_TPART + (size_t)Bv * NCv * Dv;
constexpr size_t OFF_ED    = OFF_XMAX + (size_t)Bv * Dv;
constexpr size_t OFF_TD    = OFF_ED   + (size_t)Bv * Dv;
constexpr size_t OFF_HFULL = OFF_TD   + (size_t)Bv * Dv;   // [B]
constexpr size_t OFF_HSD   = OFF_HFULL + Bv;               // [B] sum_d H_sd
constexpr size_t OFF_HBP   = OFF_HSD + Bv;                 // [B*P] sum_k H_pk

__device__ __forceinline__ float warpSum(float v) {
    for (int o = 32; o > 0; o >>= 1) v += __shfl_xor(v, o);
    return v;
}
__device__ __forceinline__ float warpMax(float v) {
    for (int o = 32; o > 0; o >>= 1) v = fmaxf(v, __shfl_xor(v, o));
    return v;
}
// 256-thread (4-wave) block reductions; red is shared float[4]; result to ALL.
__device__ __forceinline__ float blockSum256(float v, float* red) {
    float s = warpSum(v);
    int lane = threadIdx.x & 63, w = threadIdx.x >> 6;
    __syncthreads();
    if (lane == 0) red[w] = s;
    __syncthreads();
    return red[0] + red[1] + red[2] + red[3];
}
__device__ __forceinline__ float blockMax256(float v, float* red) {
    float s = warpMax(v);
    int lane = threadIdx.x & 63, w = threadIdx.x >> 6;
    __syncthreads();
    if (lane == 0) red[w] = s;
    __syncthreads();
    return fmaxf(fmaxf(red[0], red[1]), fmaxf(red[2], red[3]));
}
// 512-thread (8-wave) block sum; red is shared float[8].
__device__ __forceinline__ float blockSum512(float v, float* red) {
    float s = warpSum(v);
    int lane = threadIdx.x & 63, w = threadIdx.x >> 6;
    __syncthreads();
    if (lane == 0) red[w] = s;
    __syncthreads();
    return red[0] + red[1] + red[2] + red[3] + red[4] + red[5] + red[6] + red[7];
}

// Online softmax-stat update: (m, z, t) += element v
#define UPD(v, m, z, t)                                        \
    {                                                          \
        float vv = (v);                                        \
        if (vv > m) {                                          \
            float r = __expf(m - vv);                          \
            z = z * r + 1.0f;                                  \
            t = t * r + vv;                                    \
            m = vv;                                            \
        } else {                                               \
            float e_ = __expf(vv - m);                         \
            z += e_;                                           \
            t += e_ * vv;                                      \
        }                                                      \
    }

// Merge two stat triples. Safe when m == -inf.
__device__ __forceinline__ void mergeStats(float& m, float& z, float& t,
                                           float mb, float zb, float tb) {
    float nm = fmaxf(m, mb);
    float ra = __expf(m - nm);
    float rb = __expf(mb - nm);
    z = z * ra + zb * rb;
    t = t * ra + tb * rb;
    m = nm;
}

__device__ __forceinline__ float sigmoidf(float v) { return 1.0f / (1.0f + __expf(-v)); }

// ---------------------------------------------------------------------------
// Kernel 1 (fused with chunk-combine): pass over x, per-(b,chunk,d) online
// stats; the last block to finish for each b combines the 64 chunk partials
// into xmax/e/t[b,d], H_sd sum, and the full-flatten entropy H_full[b].
// ---------------------------------------------------------------------------
__global__ __launch_bounds__(256) void k1_fused(const float* __restrict__ x,
                                                float* __restrict__ ws,
                                                int* __restrict__ ctr) {
    int c = blockIdx.x;
    int b = blockIdx.y;
    int tid = threadIdx.x;
    int dg = tid & 127;
    int sl = tid >> 7;

    const float4* xv = (const float4*)x;
    float m0 = -INFINITY, m1 = -INFINITY, m2 = -INFINITY, m3 = -INFINITY;
    float z0 = 0.f, z1 = 0.f, z2 = 0.f, z3 = 0.f;
    float t0 = 0.f, t1 = 0.f, t2 = 0.f, t3 = 0.f;

    int sbase = c * SCv + sl;
    for (int i = 0; i < SCv / 2; i++) {
        int s = sbase + 2 * i;
        float4 v = xv[((size_t)b * Sv + s) * 128 + dg];
        UPD(v.x, m0, z0, t0);
        UPD(v.y, m1, z1, t1);
        UPD(v.z, m2, z2, t2);
        UPD(v.w, m3, z3, t3);
    }

    // merge the two s-interleaves via LDS
    __shared__ float smm[512], smz[512], smt[512];
    __shared__ float red[4];
    __shared__ int amLast;
    if (sl == 1) {
        smm[dg * 4 + 0] = m0; smm[dg * 4 + 1] = m1; smm[dg * 4 + 2] = m2; smm[dg * 4 + 3] = m3;
        smz[dg * 4 + 0] = z0; smz[dg * 4 + 1] = z1; smz[dg * 4 + 2] = z2; smz[dg * 4 + 3] = z3;
        smt[dg * 4 + 0] = t0; smt[dg * 4 + 1] = t1; smt[dg * 4 + 2] = t2; smt[dg * 4 + 3] = t3;
    }
    __syncthreads();
    if (sl == 0) {
        mergeStats(m0, z0, t0, smm[dg * 4 + 0], smz[dg * 4 + 0], smt[dg * 4 + 0]);
        mergeStats(m1, z1, t1, smm[dg * 4 + 1], smz[dg * 4 + 1], smt[dg * 4 + 1]);
        mergeStats(m2, z2, t2, smm[dg * 4 + 2], smz[dg * 4 + 2], smt[dg * 4 + 2]);
        mergeStats(m3, z3, t3, smm[dg * 4 + 3], smz[dg * 4 + 3], smt[dg * 4 + 3]);

        size_t o = ((size_t)(b * NCv + c)) * 128 + dg;   // float4 index into [.,D]
        ((float4*)(ws + OFF_MPART))[o] = make_float4(m0, m1, m2, m3);
        ((float4*)(ws + OFF_ZPART))[o] = make_float4(z0, z1, z2, z3);
        ((float4*)(ws + OFF_TPART))[o] = make_float4(t0, t1, t2, t3);
    }
    // release our partials, take a ticket; last block for this b combines.
    __threadfence();
    __syncthreads();
    if (tid == 0) {
        int old = atomicAdd(&ctr[b], 1);
        amLast = (old == NCv - 1);
    }
    __syncthreads();
    if (!amLast) return;
    __threadfence();   // acquire: make other blocks' partials visible

    const float* mp = ws + OFF_MPART;
    const float* zp = ws + OFF_ZPART;
    const float* tp = ws + OFF_TPART;
    float cm[2], cz[2], ct[2], ch[2];
    for (int r = 0; r < 2; r++) {
        int d = tid + 256 * r;
        float m = -INFINITY, z = 0.f, t = 0.f;
        for (int cc = 0; cc < NCv; cc++) {
            size_t idx = ((size_t)(b * NCv + cc)) * Dv + d;
            mergeStats(m, z, t, mp[idx], zp[idx], tp[idx]);
        }
        ws[OFF_XMAX + (size_t)b * Dv + d] = m;
        ws[OFF_ED   + (size_t)b * Dv + d] = z;
        ws[OFF_TD   + (size_t)b * Dv + d] = t;
        cm[r] = m; cz[r] = z; ct[r] = t;
        ch[r] = m + __logf(z) - t / z;    // per-(b,d) seq entropy
    }
    float hs = blockSum256(ch[0] + ch[1], red);
    float mb = blockMax256(fmaxf(cm[0], cm[1]), red);
    float s0 = __expf(cm[0] - mb), s1 = __expf(cm[1] - mb);
    float zb = blockSum256(cz[0] * s0 + cz[1] * s1, red);
    float tb = blockSum256(ct[0] * s0 + ct[1] * s1, red);
    if (tid == 0) {
        ws[OFF_HSD + b]   = hs;
        ws[OFF_HFULL + b] = mb + __logf(zb) - tb / zb;
    }
}

// ---------------------------------------------------------------------------
// Kernel 3 (fused with final head): one block per (p,b). Inline mask decode,
// group max + Z/T via wave-level masked shuffle reductions (no LDS atomics).
// The globally-last block computes the weighted-min + MLP head.
// ---------------------------------------------------------------------------
__global__ __launch_bounds__(512) void k3_fused(
    const void* __restrict__ masks,
    const float* __restrict__ es, const float* __restrict__ iw,
    const float* __restrict__ W1, const float* __restrict__ b1,
    const float* __restrict__ W2, const float* __restrict__ b2,
    const float* __restrict__ W3, const float* __restrict__ b3,
    float* __restrict__ ws, int* __restrict__ ctr,
    float* __restrict__ out) {
    int p = blockIdx.x;
    int b = blockIdx.y;
    int d = threadIdx.x;
    int lane = d & 63, w = d >> 6;

    // mask dtype self-detect: uint8-packed bools give words > 1 in the first
    // 512 words (mask density ~0.2-0.5 => near-certain); int32 words are 0/1.
    __shared__ int f;
    if (d == 0) f = 0;
    __syncthreads();
    const unsigned int* mwords = (const unsigned int*)masks;
    if (mwords[d] > 1u) atomicOr(&f, 1);
    __syncthreads();

    int mk = 255;
    if (f) {
        const unsigned char* mbyt = (const unsigned char*)masks;
        for (int k = 0; k < Kv; k++)
            if (mbyt[((size_t)p * Kv + k) * Dv + d]) { mk = k; break; }
    } else {
        const int* mint = (const int*)masks;
        for (int k = 0; k < Kv; k++)
            if (mint[((size_t)p * Kv + k) * Dv + d]) { mk = k; break; }
    }

    float xm = ws[OFF_XMAX + (size_t)b * Dv + d];
    float e  = ws[OFF_ED   + (size_t)b * Dv + d];
    float t  = ws[OFF_TD   + (size_t)b * Dv + d];

    __shared__ float lmax[8 * Kv], lz[8 * Kv], lt[8 * Kv];
    __shared__ float gmax[Kv], hk[Kv];
    __shared__ int amLast;

    // phase 1: per-group max via masked wave-max + 8-wave LDS combine
    for (int k = 0; k < Kv; k++) {
        float cv = (mk == k) ? xm : -INFINITY;
        float wm = warpMax(cv);
        if (lane == 0) lmax[w * Kv + k] = wm;
    }
    __syncthreads();
    if (d < Kv) {
        float g = lmax[d];
        for (int ww = 1; ww < 8; ww++) g = fmaxf(g, lmax[ww * Kv + d]);
        gmax[d] = g;
    }
    __syncthreads();

    // phase 2: Z/T sums scaled to the group max
    int mks = (mk < Kv) ? mk : 0;
    float g = gmax[mks];
    float s = __expf(xm - g);
    float ez = e * s, tz = t * s;
    for (int k = 0; k < Kv; k++) {
        float cz = (mk == k) ? ez : 0.f;
        float ctv = (mk == k) ? tz : 0.f;
        float sz = warpSum(cz);
        float st = warpSum(ctv);
        if (lane == 0) { lz[w * Kv + k] = sz; lt[w * Kv + k] = st; }
    }
    __syncthreads();
    if (d < Kv) {
        float Z = 0.f, T = 0.f;
        for (int ww = 0; ww < 8; ww++) { Z += lz[ww * Kv + d]; T += lt[ww * Kv + d]; }
        float gm = gmax[d];
        hk[d] = (gm > -INFINITY) ? gm + __logf(Z) - T / Z : 0.f;
    }
    __syncthreads();
    if (d == 0)
        ws[OFF_HBP + (size_t)b * Pv + p] = hk[0] + hk[1] + hk[2] + hk[3] + hk[4] + hk[5];

    // ticket; globally-last block runs the head
    __threadfence();
    __syncthreads();
    if (d == 0) {
        int old = atomicAdd(&ctr[8], 1);
        amLast = (old == Pv * Bv - 1);
    }
    __syncthreads();
    if (!amLast) return;
    __threadfence();   // acquire: all HBP values visible

    __shared__ float wgt[MAXPv];
    __shared__ float meanH_s;
    __shared__ float red8[8];

    float es_mean = blockSum512(es[d], red8) * (1.0f / Dv);

    if (d < Pv) {
        float sacc = 0.f;
        for (int bb = 0; bb < Bv; bb++) sacc += ws[OFF_HBP + (size_t)bb * Pv + d];
        wgt[d + 2] = (sacc * (1.0f / Bv)) * sigmoidf(iw[d + 2]);
    } else if (d == Pv) {            // h_whole
        float sacc = 0.f;
        for (int bb = 0; bb < Bv; bb++) sacc += ws[OFF_HFULL + bb];
        float mh = sacc * (1.0f / Bv);
        meanH_s = mh;
        wgt[0] = mh * sigmoidf(iw[0]);
    } else if (d == Pv + 1) {        // h_single
        float sacc = 0.f;
        for (int bb = 0; bb < Bv; bb++) sacc += ws[OFF_HSD + bb];
        wgt[1] = (sacc * (1.0f / Bv)) * sigmoidf(iw[1]);
    }
    __syncthreads();

    if (d == 0) {
        float mn = wgt[0];
        for (int i = 1; i < MAXPv; i++) mn = fminf(mn, wgt[i]);
        float raw = es_mean * meanH_s - mn;
        float z = fminf(fmaxf(raw * 0.1f, 0.0f), 1.0f);

        float h1[32];
        for (int j = 0; j < 32; j++) {
            float a = z * W1[j] + b1[j];
            h1[j] = a > 0.f ? a : 0.f;
        }
        float h2[16];
        for (int i = 0; i < 16; i++) {
            float a = b2[i];
            for (int j = 0; j < 32; j++) a += W2[i * 32 + j] * h1[j];
            h2[i] = a > 0.f ? a : 0.f;
        }
        float a = b3[0];
        for (int i = 0; i < 16; i++) a += W3[i] * h2[i];
        out[0] = sigmoidf(a);
    }
}

extern "C" void kernel_launch(void* const* d_in, const int* in_sizes, int n_in,
                              void* d_out, int out_size, void* d_ws, size_t ws_size,
                              hipStream_t stream) {
    const float* x  = (const float*)d_in[0];
    const float* es = (const float*)d_in[1];
    const float* iw = (const float*)d_in[2];
    const float* W1 = (const float*)d_in[3];
    const float* b1 = (const float*)d_in[4];
    const float* W2 = (const float*)d_in[5];
    const float* b2 = (const float*)d_in[6];
    const float* W3 = (const float*)d_in[7];
    const float* b3 = (const float*)d_in[8];
    const void* masks = d_in[9];
    float* ws = (float*)d_ws;
    int* ctr = (int*)d_ws;
    float* out = (float*)d_out;

    // zero the 16 ticket counters (graph-capture-legal memset node)
    hipMemsetAsync(d_ws, 0, 16 * sizeof(int), stream);
    k1_fused<<<dim3(NCv, Bv), dim3(256), 0, stream>>>(x, ws, ctr);
    k3_fused<<<dim3(Pv, Bv), dim3(512), 0, stream>>>(masks, es, iw, W1, b1, W2, b2,
                                                     W3, b3, ws, ctr, out);
}

// Round 3
// 155.586 us; speedup vs baseline: 1.9389x; 1.9389x over previous
//
#include <hip/hip_runtime.h>
#include <math.h>

// Problem constants (fixed by reference setup_inputs)
constexpr int Bv = 8;
constexpr int Sv = 4096;
constexpr int Dv = 512;
constexpr int NCv = 64;           // S-chunks for pass-1 partials
constexpr int SCv = Sv / NCv;     // 64 rows per chunk
constexpr int Pv = 98;            // sampled partitions
constexpr int Kv = 6;             // max parts per partition
constexpr int MAXPv = 100;

// Workspace layout (float offsets). No counters, no fences — kernel launch
// boundaries provide inter-kernel coherence (per-block device-scope fences
// measured ~100us total in round 2: each forces per-XCD L2 wb/inv).
constexpr size_t OFF_MPART = 0;
constexpr size_t OFF_ZPART = OFF_MPART + (size_t)Bv * NCv * Dv;
constexpr size_t OFF_TPART = OFF_ZPART + (size_t)Bv * NCv * Dv;
constexpr size_t OFF_XMAX  = OFF_TPART + (size_t)Bv * NCv * Dv;
constexpr size_t OFF_ED    = OFF_XMAX + (size_t)Bv * Dv;
constexpr size_t OFF_TD    = OFF_ED   + (size_t)Bv * Dv;
constexpr size_t OFF_HFULL = OFF_TD   + (size_t)Bv * Dv;   // [B]
constexpr size_t OFF_HSD   = OFF_HFULL + Bv;               // [B] sum_d H_sd
constexpr size_t OFF_HBP   = OFF_HSD + Bv;                 // [B*P] sum_k H_pk

__device__ __forceinline__ float warpSum(float v) {
    for (int o = 32; o > 0; o >>= 1) v += __shfl_xor(v, o);
    return v;
}
__device__ __forceinline__ float warpMax(float v) {
    for (int o = 32; o > 0; o >>= 1) v = fmaxf(v, __shfl_xor(v, o));
    return v;
}
// 512-thread (8-wave) block reductions; red is shared float[8]; result to ALL.
__device__ __forceinline__ float blockSum512(float v, float* red) {
    float s = warpSum(v);
    int lane = threadIdx.x & 63, w = threadIdx.x >> 6;
    __syncthreads();
    if (lane == 0) red[w] = s;
    __syncthreads();
    return red[0] + red[1] + red[2] + red[3] + red[4] + red[5] + red[6] + red[7];
}
__device__ __forceinline__ float blockMax512(float v, float* red) {
    float s = warpMax(v);
    int lane = threadIdx.x & 63, w = threadIdx.x >> 6;
    __syncthreads();
    if (lane == 0) red[w] = s;
    __syncthreads();
    float m = red[0];
    for (int i = 1; i < 8; i++) m = fmaxf(m, red[i]);
    return m;
}

// Online softmax-stat update: (m, z, t) += element v
#define UPD(v, m, z, t)                                        \
    {                                                          \
        float vv = (v);                                        \
        if (vv > m) {                                          \
            float r = __expf(m - vv);                          \
            z = z * r + 1.0f;                                  \
            t = t * r + vv;                                    \
            m = vv;                                            \
        } else {                                               \
            float e_ = __expf(vv - m);                         \
            z += e_;                                           \
            t += e_ * vv;                                      \
        }                                                      \
    }

// Merge two stat triples. Safe when m == -inf.
__device__ __forceinline__ void mergeStats(float& m, float& z, float& t,
                                           float mb, float zb, float tb) {
    float nm = fmaxf(m, mb);
    float ra = __expf(m - nm);
    float rb = __expf(mb - nm);
    z = z * ra + zb * rb;
    t = t * ra + tb * rb;
    m = nm;
}

__device__ __forceinline__ float sigmoidf(float v) { return 1.0f / (1.0f + __expf(-v)); }

// ---------------------------------------------------------------------------
// Kernel 1: pass over x, per-(b,chunk,d) online stats (m, Z, T).
// Block = 256 threads: tid&127 -> d-group (4 consecutive d via float4),
// tid>>7 -> s interleave (2 sub-accumulators merged in LDS).
// ---------------------------------------------------------------------------
__global__ __launch_bounds__(256) void k1_partial(const float* __restrict__ x,
                                                  float* __restrict__ ws) {
    int c = blockIdx.x;
    int b = blockIdx.y;
    int tid = threadIdx.x;
    int dg = tid & 127;
    int sl = tid >> 7;

    const float4* xv = (const float4*)x;
    float m0 = -INFINITY, m1 = -INFINITY, m2 = -INFINITY, m3 = -INFINITY;
    float z0 = 0.f, z1 = 0.f, z2 = 0.f, z3 = 0.f;
    float t0 = 0.f, t1 = 0.f, t2 = 0.f, t3 = 0.f;

    int sbase = c * SCv + sl;
    for (int i = 0; i < SCv / 2; i++) {
        int s = sbase + 2 * i;
        float4 v = xv[((size_t)b * Sv + s) * 128 + dg];
        UPD(v.x, m0, z0, t0);
        UPD(v.y, m1, z1, t1);
        UPD(v.z, m2, z2, t2);
        UPD(v.w, m3, z3, t3);
    }

    // merge the two s-interleaves via LDS
    __shared__ float smm[512], smz[512], smt[512];
    if (sl == 1) {
        smm[dg * 4 + 0] = m0; smm[dg * 4 + 1] = m1; smm[dg * 4 + 2] = m2; smm[dg * 4 + 3] = m3;
        smz[dg * 4 + 0] = z0; smz[dg * 4 + 1] = z1; smz[dg * 4 + 2] = z2; smz[dg * 4 + 3] = z3;
        smt[dg * 4 + 0] = t0; smt[dg * 4 + 1] = t1; smt[dg * 4 + 2] = t2; smt[dg * 4 + 3] = t3;
    }
    __syncthreads();
    if (sl == 0) {
        mergeStats(m0, z0, t0, smm[dg * 4 + 0], smz[dg * 4 + 0], smt[dg * 4 + 0]);
        mergeStats(m1, z1, t1, smm[dg * 4 + 1], smz[dg * 4 + 1], smt[dg * 4 + 1]);
        mergeStats(m2, z2, t2, smm[dg * 4 + 2], smz[dg * 4 + 2], smt[dg * 4 + 2]);
        mergeStats(m3, z3, t3, smm[dg * 4 + 3], smz[dg * 4 + 3], smt[dg * 4 + 3]);

        size_t o = ((size_t)(b * NCv + c)) * 128 + dg;   // float4 index into [.,D]
        ((float4*)(ws + OFF_MPART))[o] = make_float4(m0, m1, m2, m3);
        ((float4*)(ws + OFF_ZPART))[o] = make_float4(z0, z1, z2, z3);
        ((float4*)(ws + OFF_TPART))[o] = make_float4(t0, t1, t2, t3);
    }
}

// ---------------------------------------------------------------------------
// Kernel 2: combine chunk partials per (b,d); emit xmax/e/t arrays, per-b
// H_sd sum, and per-b full-flatten entropy.
// ---------------------------------------------------------------------------
__global__ __launch_bounds__(512) void k2_combine(float* __restrict__ ws) {
    int b = blockIdx.x;
    int d = threadIdx.x;
    const float* mp = ws + OFF_MPART;
    const float* zp = ws + OFF_ZPART;
    const float* tp = ws + OFF_TPART;

    float m = -INFINITY, z = 0.f, t = 0.f;
    for (int c = 0; c < NCv; c++) {
        size_t idx = ((size_t)(b * NCv + c)) * Dv + d;
        mergeStats(m, z, t, mp[idx], zp[idx], tp[idx]);
    }

    ws[OFF_XMAX + (size_t)b * Dv + d] = m;
    ws[OFF_ED   + (size_t)b * Dv + d] = z;
    ws[OFF_TD   + (size_t)b * Dv + d] = t;

    float hsd = m + __logf(z) - t / z;   // per-(b,d) seq entropy

    __shared__ float red[8];
    float sum_h = blockSum512(hsd, red);
    float mb = blockMax512(m, red);
    float sc = __expf(m - mb);
    float zb = blockSum512(z * sc, red);
    float tb = blockSum512(t * sc, red);
    if (d == 0) {
        ws[OFF_HSD + b] = sum_h;
        ws[OFF_HFULL + b] = mb + __logf(zb) - tb / zb;
    }
}

// ---------------------------------------------------------------------------
// Kernel 3: sampled partitions. One block per (p,b). Inline mask decode;
// group max + Z/T via wave-level masked shuffle reductions (no LDS atomics).
// ---------------------------------------------------------------------------
__global__ __launch_bounds__(512) void k3_parts(const void* __restrict__ masks,
                                                float* __restrict__ ws) {
    int p = blockIdx.x;
    int b = blockIdx.y;
    int d = threadIdx.x;
    int lane = d & 63, w = d >> 6;

    // mask dtype self-detect: uint8-packed bools give words > 1 in the first
    // 512 words (mask density ~0.2-0.5 => near-certain); int32 words are 0/1.
    // Benign write race: every racing thread writes the same value.
    __shared__ int f;
    if (d == 0) f = 0;
    __syncthreads();
    const unsigned int* mwords = (const unsigned int*)masks;
    if (mwords[d] > 1u) f = 1;
    __syncthreads();

    int mk = 255;
    if (f) {
        const unsigned char* mbyt = (const unsigned char*)masks;
        for (int k = 0; k < Kv; k++)
            if (mbyt[((size_t)p * Kv + k) * Dv + d]) { mk = k; break; }
    } else {
        const int* mint = (const int*)masks;
        for (int k = 0; k < Kv; k++)
            if (mint[((size_t)p * Kv + k) * Dv + d]) { mk = k; break; }
    }

    float xm = ws[OFF_XMAX + (size_t)b * Dv + d];
    float e  = ws[OFF_ED   + (size_t)b * Dv + d];
    float t  = ws[OFF_TD   + (size_t)b * Dv + d];

    __shared__ float lmax[8 * Kv], lz[8 * Kv], lt[8 * Kv];
    __shared__ float gmax[Kv], hk[Kv];

    // phase 1: per-group max via masked wave-max + 8-wave LDS combine
    for (int k = 0; k < Kv; k++) {
        float cv = (mk == k) ? xm : -INFINITY;
        float wm = warpMax(cv);
        if (lane == 0) lmax[w * Kv + k] = wm;
    }
    __syncthreads();
    if (d < Kv) {
        float g = lmax[d];
        for (int ww = 1; ww < 8; ww++) g = fmaxf(g, lmax[ww * Kv + d]);
        gmax[d] = g;
    }
    __syncthreads();

    // phase 2: Z/T sums scaled to the group max
    int mks = (mk < Kv) ? mk : 0;
    float g = gmax[mks];
    float s = __expf(xm - g);
    float ez = e * s, tz = t * s;
    for (int k = 0; k < Kv; k++) {
        float cz = (mk == k) ? ez : 0.f;
        float ctv = (mk == k) ? tz : 0.f;
        float sz = warpSum(cz);
        float st = warpSum(ctv);
        if (lane == 0) { lz[w * Kv + k] = sz; lt[w * Kv + k] = st; }
    }
    __syncthreads();
    if (d < Kv) {
        float Z = 0.f, T = 0.f;
        for (int ww = 0; ww < 8; ww++) { Z += lz[ww * Kv + d]; T += lt[ww * Kv + d]; }
        float gm = gmax[d];
        hk[d] = (gm > -INFINITY) ? gm + __logf(Z) - T / Z : 0.f;
    }
    __syncthreads();
    if (d == 0)
        ws[OFF_HBP + (size_t)b * Pv + p] = hk[0] + hk[1] + hk[2] + hk[3] + hk[4] + hk[5];
}

// ---------------------------------------------------------------------------
// Kernel 4: combine 100 partition entropies, weighted min, MLP head.
// ---------------------------------------------------------------------------
__global__ __launch_bounds__(128) void k4_final(
    const float* __restrict__ es, const float* __restrict__ iw,
    const float* __restrict__ W1, const float* __restrict__ b1,
    const float* __restrict__ W2, const float* __restrict__ b2,
    const float* __restrict__ W3, const float* __restrict__ b3,
    const float* __restrict__ ws, float* __restrict__ out) {
    int tid = threadIdx.x;
    __shared__ float wgt[MAXPv];
    __shared__ float meanH_s;
    __shared__ float red[2];

    // mean(entropy_scales) over 512 elems
    float v = es[tid] + es[tid + 128] + es[tid + 256] + es[tid + 384];
    float s64 = warpSum(v);
    int lane = tid & 63, w = tid >> 6;
    if (lane == 0) red[w] = s64;
    __syncthreads();
    float es_mean = (red[0] + red[1]) * (1.0f / 512.0f);

    if (tid < Pv) {
        float s = 0.f;
        for (int b = 0; b < Bv; b++) s += ws[OFF_HBP + (size_t)b * Pv + tid];
        wgt[tid + 2] = (s * (1.0f / Bv)) * sigmoidf(iw[tid + 2]);
    } else if (tid == Pv) {          // h_whole
        float s = 0.f;
        for (int b = 0; b < Bv; b++) s += ws[OFF_HFULL + b];
        float mh = s * (1.0f / Bv);
        meanH_s = mh;
        wgt[0] = mh * sigmoidf(iw[0]);
    } else if (tid == Pv + 1) {      // h_single
        float s = 0.f;
        for (int b = 0; b < Bv; b++) s += ws[OFF_HSD + b];
        wgt[1] = (s * (1.0f / Bv)) * sigmoidf(iw[1]);
    }
    __syncthreads();

    if (tid == 0) {
        float mn = wgt[0];
        for (int i = 1; i < MAXPv; i++) mn = fminf(mn, wgt[i]);
        float raw = es_mean * meanH_s - mn;
        float z = fminf(fmaxf(raw * 0.1f, 0.0f), 1.0f);

        float h1[32];
        for (int j = 0; j < 32; j++) {
            float a = z * W1[j] + b1[j];
            h1[j] = a > 0.f ? a : 0.f;
        }
        float h2[16];
        for (int i = 0; i < 16; i++) {
            float a = b2[i];
            for (int j = 0; j < 32; j++) a += W2[i * 32 + j] * h1[j];
            h2[i] = a > 0.f ? a : 0.f;
        }
        float a = b3[0];
        for (int i = 0; i < 16; i++) a += W3[i] * h2[i];
        out[0] = sigmoidf(a);
    }
}

extern "C" void kernel_launch(void* const* d_in, const int* in_sizes, int n_in,
                              void* d_out, int out_size, void* d_ws, size_t ws_size,
                              hipStream_t stream) {
    const float* x  = (const float*)d_in[0];
    const float* es = (const float*)d_in[1];
    const float* iw = (const float*)d_in[2];
    const float* W1 = (const float*)d_in[3];
    const float* b1 = (const float*)d_in[4];
    const float* W2 = (const float*)d_in[5];
    const float* b2 = (const float*)d_in[6];
    const float* W3 = (const float*)d_in[7];
    const float* b3 = (const float*)d_in[8];
    const void* masks = d_in[9];
    float* ws = (float*)d_ws;
    float* out = (float*)d_out;

    k1_partial<<<dim3(NCv, Bv), dim3(256), 0, stream>>>(x, ws);
    k2_combine<<<dim3(Bv), dim3(512), 0, stream>>>(ws);
    k3_parts<<<dim3(Pv, Bv), dim3(512), 0, stream>>>(masks, ws);
    k4_final<<<dim3(1), dim3(128), 0, stream>>>(es, iw, W1, b1, W2, b2, W3, b3, ws, out);
}